// Round 5
// baseline (11130.832 us; speedup 1.0000x reference)
//
#include <hip/hip_runtime.h>
#include <hip/hip_bf16.h>

// EmbedAlign: emb gather -> 3-layer BiLSTM (seq scan) -> mu/sigma nets ->
// reparam z -> KL + negative-sampling scores + alignment marginal -> scalar.
// All fp32. D=512, L=1024, NNEG=8192, V=32000.

// ---------------------------------------------------------------------------
// Generic fp32 NT GEMM: C[M,N] = A[M,K] . B[N,K]^T (+bias) with epilogues.
// GATHER: B row n comes from B[idx[n]].  EPI: 0=store(+bias,+relu),
// 1=atomicAdd rowsum(exp(C)) into C-vector, 2=atomicAdd sum(exp/(exp+negf)).
// Tiles 64x64, BK=16, 256 threads, 4x4 per thread.
// ---------------------------------------------------------------------------
template<bool GATHER, bool RELU, int EPI>
__global__ __launch_bounds__(256) void gemm_nt(
    const float* __restrict__ A, const float* __restrict__ B,
    const float* __restrict__ bias, const int* __restrict__ idx,
    float* __restrict__ C, const float* __restrict__ negf,
    float* __restrict__ outsum, int M, int N, int K)
{
    __shared__ float As[16][68];
    __shared__ float Bs[16][68];
    __shared__ float wsum[4];

    const int tid = threadIdx.x;
    const int bm = blockIdx.x, bn = blockIdx.y;
    const int tx = tid & 15, ty = tid >> 4;
    const int lr = tid >> 2;          // 0..63: tile row being loaded
    const int lk = (tid & 3) * 4;     // 0,4,8,12: k sub-offset

    const long arow = (long)bm * 64 + lr;
    const int  brow = bn * 64 + lr;
    const long bsrc = GATHER ? (long)idx[brow] : (long)brow;
    const float* Ap = A + arow * K + lk;
    const float* Bp = B + bsrc * K + lk;

    float acc[4][4] = {};

    for (int k0 = 0; k0 < K; k0 += 16) {
        float4 av = *(const float4*)(Ap + k0);
        float4 bv = *(const float4*)(Bp + k0);
        __syncthreads();
        As[lk + 0][lr] = av.x; As[lk + 1][lr] = av.y;
        As[lk + 2][lr] = av.z; As[lk + 3][lr] = av.w;
        Bs[lk + 0][lr] = bv.x; Bs[lk + 1][lr] = bv.y;
        Bs[lk + 2][lr] = bv.z; Bs[lk + 3][lr] = bv.w;
        __syncthreads();
#pragma unroll
        for (int k = 0; k < 16; ++k) {
            float4 a = *(const float4*)&As[k][ty * 4];
            float4 b = *(const float4*)&Bs[k][tx * 4];
            float ar[4] = {a.x, a.y, a.z, a.w};
            float br[4] = {b.x, b.y, b.z, b.w};
#pragma unroll
            for (int i = 0; i < 4; ++i)
#pragma unroll
                for (int j = 0; j < 4; ++j)
                    acc[i][j] += ar[i] * br[j];
        }
    }

    const int row0 = bm * 64 + ty * 4, col0 = bn * 64 + tx * 4;

    if (EPI == 0) {
#pragma unroll
        for (int i = 0; i < 4; ++i) {
            float4 v;
            float vv[4];
#pragma unroll
            for (int j = 0; j < 4; ++j) {
                float x = acc[i][j];
                if (bias) x += bias[col0 + j];
                if (RELU) x = x > 0.f ? x : 0.f;
                vv[j] = x;
            }
            v.x = vv[0]; v.y = vv[1]; v.z = vv[2]; v.w = vv[3];
            *(float4*)&C[(long)(row0 + i) * N + col0] = v;
        }
    } else if (EPI == 1) {
        // per-row sum of exp over this tile's 64 cols -> atomicAdd C[row]
#pragma unroll
        for (int i = 0; i < 4; ++i) {
            float s = expf(acc[i][0]) + expf(acc[i][1]) +
                      expf(acc[i][2]) + expf(acc[i][3]);
            s += __shfl_xor(s, 1); s += __shfl_xor(s, 2);
            s += __shfl_xor(s, 4); s += __shfl_xor(s, 8);
            if (tx == 0) atomicAdd(&C[row0 + i], s);
        }
    } else {
        float t = 0.f;
#pragma unroll
        for (int i = 0; i < 4; ++i) {
            float nf = negf[row0 + i];
#pragma unroll
            for (int j = 0; j < 4; ++j) {
                float e = expf(acc[i][j]);
                t += e / (e + nf);
            }
        }
#pragma unroll
        for (int o = 1; o < 64; o <<= 1) t += __shfl_xor(t, o);
        if ((tid & 63) == 0) wsum[tid >> 6] = t;
        __syncthreads();
        if (tid == 0) atomicAdd(outsum, wsum[0] + wsum[1] + wsum[2] + wsum[3]);
    }
}

// ---------------------------------------------------------------------------
// BiLSTM scan, 1024 steps. Grid = 256 WGs x 256 threads: blocks 0..127
// forward, 128..255 backward (1 WG/CU). Each WG owns 4 h-outputs, ONE PER
// WAVE: wave v computes all 4 gates of h[w*4+v] (gate = lane>>4, 32 cols
// per lane). Whh staged once to LDS (reg-resident weights were demoted by
// the allocator in R1/R2), per-thread 32 floats padded to 36 (conflict-free,
// R3 verified SQ_LDS_BANK_CONFLICT=0).
//
// Per step: wave 0 polls the 512 data+tag slots (8/lane, coalesced) and
// stages h into the parity LDS buffer; ONE __syncthreads; in-wave dot +
// 16-lane butterfly; per-gate-group nonlinearity in parallel (sigmoid/tanh
// by predication); 3 shfls to lane 0; c update; publish h as one 8-byte
// relaxed agent-scope atomic (low=fp32 h, high=tag s+1). Buffers alternate
// by parity; a WG can only overwrite a buffer after all WGs published the
// intervening step, which happens after they staged (consumed) it.
// ---------------------------------------------------------------------------
__global__ __launch_bounds__(256, 1) void lstm_scan(
    const float* __restrict__ Xf, const float* __restrict__ Xb, // (1024,2048) pre-proj incl bias
    const float* __restrict__ Whh,                              // (2,2048,512)
    float* __restrict__ out,                                    // (1024,1024) [hf|hb]
    unsigned long long* __restrict__ hbuf)                      // (2 dirs,2 bufs,512 slots), zeroed
{
    const int tid  = threadIdx.x;
    const int dir  = blockIdx.x >> 7;
    const int w    = blockIdx.x & 127;
    const int v    = tid >> 6;        // wave 0..3 -> h index w*4+v
    const int ln   = tid & 63;
    const int gate = ln >> 4;         // 0..3 (i,f,g,o)
    const int ck   = ln & 15;         // col chunk, 32 cols each
    const int j    = w * 4 + v;       // owned h index 0..511
    const int grow = gate * 512 + j;  // row in (2048 x 512) Whh

    __shared__ float Wl[256 * 36];        // per-thread 32 w + 4 pad
    __shared__ float hsbuf[2][16 * 36];   // parity-double-buffered h stage

    // ---- stage this WG's Whh rows into LDS (once) ----
    {
        const float4* Wrow = (const float4*)(Whh + ((long)dir * 2048 + grow) * 512 + ck * 32);
        float4* wl4 = (float4*)Wl + tid * 9;
#pragma unroll
        for (int q = 0; q < 8; ++q) wl4[q] = Wrow[q];
    }
    __syncthreads();

    const float* Xp = dir ? Xb : Xf;
    unsigned long long* myh = hbuf + dir * 1024;

    float c = 0.f;
    bool dead = false;
    const float4* wl4 = (const float4*)Wl + tid * 9;

    for (int s = 0; s < 1024; ++s) {
        const int t = dir ? (1023 - s) : s;
        float xg = Xp[(long)t * 2048 + grow];   // broadcast within gate-group

        float* hs = hsbuf[s & 1];

        // ---- wave 0: poll h_{s-1} slots (tag==s), stage to LDS ----
        if (v == 0) {
            unsigned long long* rb = myh + ((s + 1) & 1) * 512;
            unsigned long long vv[8];
            unsigned it = 0;
            for (;;) {
                bool ok = true;
#pragma unroll
                for (int k = 0; k < 8; ++k)
                    vv[k] = __hip_atomic_load(&rb[ln * 8 + k], __ATOMIC_RELAXED,
                                              __HIP_MEMORY_SCOPE_AGENT);
#pragma unroll
                for (int k = 0; k < 8; ++k)
                    ok &= ((int)(vv[k] >> 32) == s);
                if (ok || dead) break;
                if (++it > (1u << 20)) { dead = true; break; }  // anti-hang
            }
            // slot i -> hs[(i>>5)*36 + (i&31)]; lane writes 8 consecutive
            float* hb = hs + (ln >> 2) * 36 + (ln & 3) * 8;
#pragma unroll
            for (int k = 0; k < 8; ++k) hb[k] = __uint_as_float((unsigned)vv[k]);
        }
        __syncthreads();   // the ONLY barrier per step

        // ---- in-wave dot: 4 gates x 512 cols over 64 lanes ----
        const float4* hs4 = (const float4*)hs + ck * 9;
        float a0 = 0.f, a1 = 0.f;
#pragma unroll
        for (int q = 0; q < 8; q += 2) {
            float4 w0 = wl4[q],     h0 = hs4[q];
            float4 w1 = wl4[q + 1], h1 = hs4[q + 1];
            a0 += w0.x*h0.x + w0.y*h0.y + w0.z*h0.z + w0.w*h0.w;
            a1 += w1.x*h1.x + w1.y*h1.y + w1.z*h1.z + w1.w*h1.w;
        }
        float a = a0 + a1;
        if (ck == 0) a += xg;        // add pre-projection once per gate
        a += __shfl_xor(a, 1);
        a += __shfl_xor(a, 2);
        a += __shfl_xor(a, 4);
        a += __shfl_xor(a, 8);       // butterfly within 16-lane gate group

        // per-gate nonlinearity in parallel (predicated select)
        float sgm = 1.f / (1.f + __expf(-a));
        float e2  = __expf(2.f * a);
        float th  = (e2 - 1.f) / (e2 + 1.f);
        float gv  = (gate == 2) ? th : sgm;

        float i_ = gv;                 // lane 0 holds gate 0 (i)
        float f_ = __shfl(gv, 16);
        float g_ = __shfl(gv, 32);
        float o_ = __shfl(gv, 48);

        if (ln == 0) {
            c = f_ * c + i_ * g_;
            float e2c = __expf(2.f * c);
            float h = o_ * ((e2c - 1.f) / (e2c + 1.f));
            unsigned long long pk = (unsigned long long)__float_as_uint(h)
                                  | ((unsigned long long)(unsigned)(s + 1) << 32);
            __hip_atomic_store(&myh[(s & 1) * 512 + j], pk,
                               __ATOMIC_RELAXED, __HIP_MEMORY_SCOPE_AGENT);
            out[(long)t * 1024 + dir * 512 + j] = h;   // off critical path
        }
    }
}

// ---------------------------------------------------------------------------
__global__ __launch_bounds__(128) void gather_emb(
    const int* __restrict__ en, const float* __restrict__ emb, float* __restrict__ x0)
{
    const int t = blockIdx.x;
    ((float4*)(x0 + (long)t * 512))[threadIdx.x] =
        ((const float4*)(emb + (long)en[t] * 512))[threadIdx.x];
}

__global__ __launch_bounds__(256) void add_h(
    const float* __restrict__ o2, float* __restrict__ h)
{
    const long i = (long)blockIdx.x * 256 + threadIdx.x;   // 1024*512
    const long t = i >> 9, j = i & 511;
    h[i] = o2[t * 1024 + j] + o2[t * 1024 + 512 + j];
}

__global__ __launch_bounds__(256) void zkl_kernel(
    const float* __restrict__ mu, const float* __restrict__ sp,
    const float* __restrict__ eps, float* __restrict__ z, float* __restrict__ klsum)
{
    __shared__ float w4[4];
    const int i = blockIdx.x * 256 + threadIdx.x;
    float m = mu[i], x = sp[i];
    float sg = (x > 20.f) ? x : log1pf(expf(x));   // softplus
    z[i] = m + eps[i] * sg;
    float kl = 0.5f * (sg * sg + m * m - 1.f) - logf(sg);
#pragma unroll
    for (int o = 1; o < 64; o <<= 1) kl += __shfl_xor(kl, o);
    if ((threadIdx.x & 63) == 0) w4[threadIdx.x >> 6] = kl;
    __syncthreads();
    if (threadIdx.x == 0) atomicAdd(klsum, w4[0] + w4[1] + w4[2] + w4[3]);
}

__global__ __launch_bounds__(64) void pos_kernel(
    const float* __restrict__ z, const float* __restrict__ E_en,
    const int* __restrict__ en, float* __restrict__ pos)
{
    const int t = blockIdx.x, lane = threadIdx.x;
    const float4* zr = (const float4*)(z + (long)t * 512);
    const float4* er = (const float4*)(E_en + (long)en[t] * 512);
    float s = 0.f;
#pragma unroll
    for (int q = 0; q < 2; ++q) {
        float4 a = zr[lane + q * 64], b = er[lane + q * 64];
        s += a.x * b.x + a.y * b.y + a.z * b.z + a.w * b.w;
    }
#pragma unroll
    for (int o = 1; o < 64; o <<= 1) s += __shfl_xor(s, o);
    if (lane == 0) pos[t] = expf(s);
}

__global__ __launch_bounds__(256) void finalize_kernel(
    const float* __restrict__ pos, const float* __restrict__ neg,
    const float* __restrict__ scal, float* __restrict__ out)
{
    __shared__ float w4[4];
    const int tid = threadIdx.x;
    float s = 0.f;
#pragma unroll
    for (int q = 0; q < 4; ++q) {
        int t = tid + q * 256;
        s += pos[t] / (pos[t] + neg[t]);
    }
#pragma unroll
    for (int o = 1; o < 64; o <<= 1) s += __shfl_xor(s, o);
    if ((tid & 63) == 0) w4[tid >> 6] = s;
    __syncthreads();
    if (tid == 0) {
        float sum_x = w4[0] + w4[1] + w4[2] + w4[3];
        // -(sum_x + sum_y - kl) ; sum_y = psum/1024
        out[0] = scal[0] - sum_x - scal[1] * (1.f / 1024.f);
    }
}

// ---------------------------------------------------------------------------
extern "C" void kernel_launch(void* const* d_in, const int* in_sizes, int n_in,
                              void* d_out, int out_size, void* d_ws, size_t ws_size,
                              hipStream_t stream)
{
    const int*   en     = (const int*)d_in[0];
    const int*   fr     = (const int*)d_in[1];
    const int*   en_neg = (const int*)d_in[2];
    const int*   fr_neg = (const int*)d_in[3];
    const float* emb    = (const float*)d_in[4];
    const float* Wih0   = (const float*)d_in[5];
    const float* Whh0   = (const float*)d_in[6];
    const float* b0     = (const float*)d_in[7];
    const float* Wih1   = (const float*)d_in[8];
    const float* Whh1   = (const float*)d_in[9];
    const float* b1     = (const float*)d_in[10];
    const float* Wih2   = (const float*)d_in[11];
    const float* Whh2   = (const float*)d_in[12];
    const float* b2     = (const float*)d_in[13];
    const float* Wmu1   = (const float*)d_in[14];
    const float* bmu1   = (const float*)d_in[15];
    const float* Wmu2   = (const float*)d_in[16];
    const float* bmu2   = (const float*)d_in[17];
    const float* Ws1    = (const float*)d_in[18];
    const float* bs1    = (const float*)d_in[19];
    const float* Ws2    = (const float*)d_in[20];
    const float* bs2    = (const float*)d_in[21];
    const float* E_en   = (const float*)d_in[22];
    const float* E_fr   = (const float*)d_in[23];
    const float* eps    = (const float*)d_in[24];
    float* out = (float*)d_out;

    float* w = (float*)d_ws;
    float* x0   = w;  w += 1024 * 512;
    float* bufA = w;  w += 1024 * 1024;
    float* bufB = w;  w += 1024 * 1024;
    float* Xf   = w;  w += 1024 * 2048;
    float* Xb   = w;  w += 1024 * 2048;
    float* h    = w;  w += 1024 * 512;
    float* tmp  = w;  w += 1024 * 512;
    float* mu   = w;  w += 1024 * 512;
    float* sp   = w;  w += 1024 * 512;
    float* z    = w;  w += 1024 * 512;
    float* pos  = w;  w += 1024;
    float* neg  = w;  w += 1024;
    float* negf = w;  w += 1024;                 // neg..negf contiguous
    unsigned long long* hbuf = (unsigned long long*)w; w += 4096;  // 2x2x512 slots x 8B
    float* scal = w;  w += 2;                    // [klsum, psum]

    // zero accumulators (ws is poisoned 0xAA before every launch)
    hipMemsetAsync(neg, 0, 2048 * sizeof(float), stream);
    hipMemsetAsync(scal, 0, 2 * sizeof(float), stream);

    gather_emb<<<1024, 128, 0, stream>>>(en, emb, x0);

    // ---- layer 0 (in = x0, K=512) -> bufA
    gemm_nt<false, false, 0><<<dim3(16, 32), 256, 0, stream>>>(
        x0, Wih0,               b0,        nullptr, Xf, nullptr, nullptr, 1024, 2048, 512);
    gemm_nt<false, false, 0><<<dim3(16, 32), 256, 0, stream>>>(
        x0, Wih0 + 2048 * 512,  b0 + 2048, nullptr, Xb, nullptr, nullptr, 1024, 2048, 512);
    hipMemsetAsync(hbuf, 0, 4096 * 8, stream);
    lstm_scan<<<256, 256, 0, stream>>>(Xf, Xb, Whh0, bufA, hbuf);

    // ---- layer 1 (in = bufA, K=1024) -> bufB
    gemm_nt<false, false, 0><<<dim3(16, 32), 256, 0, stream>>>(
        bufA, Wih1,               b1,        nullptr, Xf, nullptr, nullptr, 1024, 2048, 1024);
    gemm_nt<false, false, 0><<<dim3(16, 32), 256, 0, stream>>>(
        bufA, Wih1 + 2048 * 1024, b1 + 2048, nullptr, Xb, nullptr, nullptr, 1024, 2048, 1024);
    hipMemsetAsync(hbuf, 0, 4096 * 8, stream);
    lstm_scan<<<256, 256, 0, stream>>>(Xf, Xb, Whh1, bufB, hbuf);

    // ---- layer 2 (in = bufB, K=1024) -> bufA
    gemm_nt<false, false, 0><<<dim3(16, 32), 256, 0, stream>>>(
        bufB, Wih2,               b2,        nullptr, Xf, nullptr, nullptr, 1024, 2048, 1024);
    gemm_nt<false, false, 0><<<dim3(16, 32), 256, 0, stream>>>(
        bufB, Wih2 + 2048 * 1024, b2 + 2048, nullptr, Xb, nullptr, nullptr, 1024, 2048, 1024);
    hipMemsetAsync(hbuf, 0, 4096 * 8, stream);
    lstm_scan<<<256, 256, 0, stream>>>(Xf, Xb, Whh2, bufA, hbuf);

    // h = hf + hb
    add_h<<<2048, 256, 0, stream>>>(bufA, h);

    // inference nets
    gemm_nt<false, true, 0><<<dim3(16, 8), 256, 0, stream>>>(
        h,   Wmu1, bmu1, nullptr, tmp, nullptr, nullptr, 1024, 512, 512);
    gemm_nt<false, false, 0><<<dim3(16, 8), 256, 0, stream>>>(
        tmp, Wmu2, bmu2, nullptr, mu,  nullptr, nullptr, 1024, 512, 512);
    gemm_nt<false, true, 0><<<dim3(16, 8), 256, 0, stream>>>(
        h,   Ws1,  bs1,  nullptr, tmp, nullptr, nullptr, 1024, 512, 512);
    gemm_nt<false, false, 0><<<dim3(16, 8), 256, 0, stream>>>(
        tmp, Ws2,  bs2,  nullptr, sp,  nullptr, nullptr, 1024, 512, 512);

    // z, KL
    zkl_kernel<<<2048, 256, 0, stream>>>(mu, sp, eps, z, scal);

    // scores
    pos_kernel<<<1024, 64, 0, stream>>>(z, E_en, en, pos);
    gemm_nt<true, false, 1><<<dim3(16, 128), 256, 0, stream>>>(
        z, E_en, nullptr, en_neg, neg,  nullptr, nullptr, 1024, 8192, 512);
    gemm_nt<true, false, 1><<<dim3(16, 128), 256, 0, stream>>>(
        z, E_fr, nullptr, fr_neg, negf, nullptr, nullptr, 1024, 8192, 512);
    gemm_nt<true, false, 2><<<dim3(16, 16), 256, 0, stream>>>(
        z, E_fr, nullptr, fr,     nullptr, negf, scal + 1, 1024, 1024, 512);

    finalize_kernel<<<1, 256, 0, stream>>>(pos, neg, scal, out);
}

// Round 6
// 7950.430 us; speedup vs baseline: 1.4000x; 1.4000x over previous
//
#include <hip/hip_runtime.h>
#include <hip/hip_bf16.h>

// EmbedAlign: emb gather -> 3-layer BiLSTM (seq scan) -> mu/sigma nets ->
// reparam z -> KL + negative-sampling scores + alignment marginal -> scalar.
// All fp32. D=512, L=1024, NNEG=8192, V=32000.

// ---------------------------------------------------------------------------
// Generic fp32 NT GEMM: C[M,N] = A[M,K] . B[N,K]^T (+bias) with epilogues.
// GATHER: B row n comes from B[idx[n]].  EPI: 0=store(+bias,+relu),
// 1=atomicAdd rowsum(exp(C)) into C-vector, 2=atomicAdd sum(exp/(exp+negf)).
// Tiles 64x64, BK=16, 256 threads, 4x4 per thread.
// ---------------------------------------------------------------------------
template<bool GATHER, bool RELU, int EPI>
__global__ __launch_bounds__(256) void gemm_nt(
    const float* __restrict__ A, const float* __restrict__ B,
    const float* __restrict__ bias, const int* __restrict__ idx,
    float* __restrict__ C, const float* __restrict__ negf,
    float* __restrict__ outsum, int M, int N, int K)
{
    __shared__ float As[16][68];
    __shared__ float Bs[16][68];
    __shared__ float wsum[4];

    const int tid = threadIdx.x;
    const int bm = blockIdx.x, bn = blockIdx.y;
    const int tx = tid & 15, ty = tid >> 4;
    const int lr = tid >> 2;          // 0..63: tile row being loaded
    const int lk = (tid & 3) * 4;     // 0,4,8,12: k sub-offset

    const long arow = (long)bm * 64 + lr;
    const int  brow = bn * 64 + lr;
    const long bsrc = GATHER ? (long)idx[brow] : (long)brow;
    const float* Ap = A + arow * K + lk;
    const float* Bp = B + bsrc * K + lk;

    float acc[4][4] = {};

    for (int k0 = 0; k0 < K; k0 += 16) {
        float4 av = *(const float4*)(Ap + k0);
        float4 bv = *(const float4*)(Bp + k0);
        __syncthreads();
        As[lk + 0][lr] = av.x; As[lk + 1][lr] = av.y;
        As[lk + 2][lr] = av.z; As[lk + 3][lr] = av.w;
        Bs[lk + 0][lr] = bv.x; Bs[lk + 1][lr] = bv.y;
        Bs[lk + 2][lr] = bv.z; Bs[lk + 3][lr] = bv.w;
        __syncthreads();
#pragma unroll
        for (int k = 0; k < 16; ++k) {
            float4 a = *(const float4*)&As[k][ty * 4];
            float4 b = *(const float4*)&Bs[k][tx * 4];
            float ar[4] = {a.x, a.y, a.z, a.w};
            float br[4] = {b.x, b.y, b.z, b.w};
#pragma unroll
            for (int i = 0; i < 4; ++i)
#pragma unroll
                for (int j = 0; j < 4; ++j)
                    acc[i][j] += ar[i] * br[j];
        }
    }

    const int row0 = bm * 64 + ty * 4, col0 = bn * 64 + tx * 4;

    if (EPI == 0) {
#pragma unroll
        for (int i = 0; i < 4; ++i) {
            float4 v;
            float vv[4];
#pragma unroll
            for (int j = 0; j < 4; ++j) {
                float x = acc[i][j];
                if (bias) x += bias[col0 + j];
                if (RELU) x = x > 0.f ? x : 0.f;
                vv[j] = x;
            }
            v.x = vv[0]; v.y = vv[1]; v.z = vv[2]; v.w = vv[3];
            *(float4*)&C[(long)(row0 + i) * N + col0] = v;
        }
    } else if (EPI == 1) {
        // per-row sum of exp over this tile's 64 cols -> atomicAdd C[row]
#pragma unroll
        for (int i = 0; i < 4; ++i) {
            float s = expf(acc[i][0]) + expf(acc[i][1]) +
                      expf(acc[i][2]) + expf(acc[i][3]);
            s += __shfl_xor(s, 1); s += __shfl_xor(s, 2);
            s += __shfl_xor(s, 4); s += __shfl_xor(s, 8);
            if (tx == 0) atomicAdd(&C[row0 + i], s);
        }
    } else {
        float t = 0.f;
#pragma unroll
        for (int i = 0; i < 4; ++i) {
            float nf = negf[row0 + i];
#pragma unroll
            for (int j = 0; j < 4; ++j) {
                float e = expf(acc[i][j]);
                t += e / (e + nf);
            }
        }
#pragma unroll
        for (int o = 1; o < 64; o <<= 1) t += __shfl_xor(t, o);
        if ((tid & 63) == 0) wsum[tid >> 6] = t;
        __syncthreads();
        if (tid == 0) atomicAdd(outsum, wsum[0] + wsum[1] + wsum[2] + wsum[3]);
    }
}

// ---------------------------------------------------------------------------
// BiLSTM scan, 1024 steps, BOTH directions per WG. Grid = 128 WGs x 256
// threads; WG w owns h-outputs [w*4, w*4+4) of the forward chain AND of the
// backward chain. Per combined iteration: poll A, compute+publish A, poll B,
// compute+publish B -- chain A's publish->visibility MALL round trip elapses
// while the WG computes chain B, hiding the latency that R3/R4 exposed
// (R4's local-work trims regressed; the floor is MALL RT + poll-traffic
// queueing, not VALU).
//
// Per-chain structure is exactly R3's proven one (2048 us): Whh in LDS
// (reg-resident weights get demoted by the allocator), per-thread 32 floats
// padded to 36 (SQ_LDS_BANK_CONFLICT=0 verified), 16 rows x 16 chunks,
// 4-lane... 16-lane butterfly, 4-thread gate tail. Exchange: one 8-byte
// relaxed agent-scope atomic per h (low=fp32, high=tag s+1), parity double
// buffer; s_sleep backoff on poll miss to cut fabric pressure.
// ---------------------------------------------------------------------------
__global__ __launch_bounds__(256, 1) void lstm_scan(
    const float* __restrict__ Xf, const float* __restrict__ Xb, // (1024,2048) pre-proj incl bias
    const float* __restrict__ Whh,                              // (2,2048,512)
    float* __restrict__ out,                                    // (1024,1024) [hf|hb]
    unsigned long long* __restrict__ hbuf)                      // (2 dirs,2 bufs,512 slots), zeroed
{
    const int tid  = threadIdx.x;
    const int w    = blockIdx.x;      // 0..127
    const int r    = tid >> 4;        // 0..15 gate-row within WG
    const int ck   = tid & 15;        // col chunk 0..15 (32 cols each)
    const int gate = r >> 2;
    const int jl   = r & 3;
    const int j    = w * 4 + jl;      // h index 0..511
    const int grow = gate * 512 + j;  // row in (2048 x 512) Whh

    __shared__ float WlA[256 * 36];   // fwd weights: per-thread 32 + 4 pad
    __shared__ float WlB[256 * 36];   // bwd weights
    __shared__ float hsA[16 * 36];
    __shared__ float hsB[16 * 36];
    __shared__ float gaA[16];
    __shared__ float gaB[16];

    // ---- stage both Whh chunks into LDS (once) ----
    {
        const float4* WrowA = (const float4*)(Whh + (long)grow * 512 + ck * 32);
        const float4* WrowB = (const float4*)(Whh + (long)(2048 + grow) * 512 + ck * 32);
        float4* wla = (float4*)WlA + tid * 9;
        float4* wlb = (float4*)WlB + tid * 9;
#pragma unroll
        for (int q = 0; q < 8; ++q) { wla[q] = WrowA[q]; wlb[q] = WrowB[q]; }
    }
    __syncthreads();

    unsigned long long* hb0 = hbuf;          // fwd: 2 parities x 512
    unsigned long long* hb1 = hbuf + 1024;   // bwd

    const float4* wla4 = (const float4*)WlA + tid * 9;
    const float4* wlb4 = (const float4*)WlB + tid * 9;
    const float4* hsa4 = (const float4*)hsA + ck * 9;
    const float4* hsb4 = (const float4*)hsB + ck * 9;

    float cA = 0.f, cB = 0.f;
    bool deadA = false, deadB = false;

    for (int s = 0; s < 1024; ++s) {
        const int tA = s, tB = 1023 - s;
        float xgA = Xf[(long)tA * 2048 + grow];
        float xgB = Xb[(long)tB * 2048 + grow];

        // ================= chain A (forward) =================
        {
            unsigned long long* rb = hb0 + ((s + 1) & 1) * 512;
            unsigned long long v0, v1;
            unsigned it = 0;
            for (;;) {
                v0 = __hip_atomic_load(&rb[tid],       __ATOMIC_RELAXED, __HIP_MEMORY_SCOPE_AGENT);
                v1 = __hip_atomic_load(&rb[tid + 256], __ATOMIC_RELAXED, __HIP_MEMORY_SCOPE_AGENT);
                if (deadA || ((int)(v0 >> 32) == s && (int)(v1 >> 32) == s)) break;
                __builtin_amdgcn_s_sleep(1);
                if (++it > (1u << 20)) { deadA = true; break; }
            }
            hsA[(tid >> 5) * 36 + (tid & 31)]         = __uint_as_float((unsigned)v0);
            hsA[((tid + 256) >> 5) * 36 + (tid & 31)] = __uint_as_float((unsigned)v1);
            __syncthreads();

            float a0 = 0.f, a1 = 0.f;
#pragma unroll
            for (int q = 0; q < 8; q += 2) {
                float4 w0 = wla4[q],     h0 = hsa4[q];
                float4 w1 = wla4[q + 1], h1 = hsa4[q + 1];
                a0 += w0.x*h0.x + w0.y*h0.y + w0.z*h0.z + w0.w*h0.w;
                a1 += w1.x*h1.x + w1.y*h1.y + w1.z*h1.z + w1.w*h1.w;
            }
            float acc = a0 + a1;
            acc += __shfl_xor(acc, 1);
            acc += __shfl_xor(acc, 2);
            acc += __shfl_xor(acc, 4);
            acc += __shfl_xor(acc, 8);
            if (ck == 0) gaA[r] = acc + xgA;
            __syncthreads();

            if (tid < 4) {
                float gi = gaA[tid], gf = gaA[4 + tid], gg = gaA[8 + tid], go = gaA[12 + tid];
                float i_ = 1.f / (1.f + __expf(-gi));
                float f_ = 1.f / (1.f + __expf(-gf));
                float eg = __expf(2.f * gg);
                float g_ = (eg - 1.f) / (eg + 1.f);
                float o_ = 1.f / (1.f + __expf(-go));
                cA = f_ * cA + i_ * g_;
                float ec = __expf(2.f * cA);
                float h = o_ * ((ec - 1.f) / (ec + 1.f));
                unsigned long long pk = (unsigned long long)__float_as_uint(h)
                                      | ((unsigned long long)(unsigned)(s + 1) << 32);
                __hip_atomic_store(&hb0[(s & 1) * 512 + w * 4 + tid], pk,
                                   __ATOMIC_RELAXED, __HIP_MEMORY_SCOPE_AGENT);
                out[(long)tA * 1024 + w * 4 + tid] = h;
            }
        }

        // ================= chain B (backward) =================
        {
            unsigned long long* rb = hb1 + ((s + 1) & 1) * 512;
            unsigned long long v0, v1;
            unsigned it = 0;
            for (;;) {
                v0 = __hip_atomic_load(&rb[tid],       __ATOMIC_RELAXED, __HIP_MEMORY_SCOPE_AGENT);
                v1 = __hip_atomic_load(&rb[tid + 256], __ATOMIC_RELAXED, __HIP_MEMORY_SCOPE_AGENT);
                if (deadB || ((int)(v0 >> 32) == s && (int)(v1 >> 32) == s)) break;
                __builtin_amdgcn_s_sleep(1);
                if (++it > (1u << 20)) { deadB = true; break; }
            }
            hsB[(tid >> 5) * 36 + (tid & 31)]         = __uint_as_float((unsigned)v0);
            hsB[((tid + 256) >> 5) * 36 + (tid & 31)] = __uint_as_float((unsigned)v1);
            __syncthreads();

            float a0 = 0.f, a1 = 0.f;
#pragma unroll
            for (int q = 0; q < 8; q += 2) {
                float4 w0 = wlb4[q],     h0 = hsb4[q];
                float4 w1 = wlb4[q + 1], h1 = hsb4[q + 1];
                a0 += w0.x*h0.x + w0.y*h0.y + w0.z*h0.z + w0.w*h0.w;
                a1 += w1.x*h1.x + w1.y*h1.y + w1.z*h1.z + w1.w*h1.w;
            }
            float acc = a0 + a1;
            acc += __shfl_xor(acc, 1);
            acc += __shfl_xor(acc, 2);
            acc += __shfl_xor(acc, 4);
            acc += __shfl_xor(acc, 8);
            if (ck == 0) gaB[r] = acc + xgB;
            __syncthreads();

            if (tid < 4) {
                float gi = gaB[tid], gf = gaB[4 + tid], gg = gaB[8 + tid], go = gaB[12 + tid];
                float i_ = 1.f / (1.f + __expf(-gi));
                float f_ = 1.f / (1.f + __expf(-gf));
                float eg = __expf(2.f * gg);
                float g_ = (eg - 1.f) / (eg + 1.f);
                float o_ = 1.f / (1.f + __expf(-go));
                cB = f_ * cB + i_ * g_;
                float ec = __expf(2.f * cB);
                float h = o_ * ((ec - 1.f) / (ec + 1.f));
                unsigned long long pk = (unsigned long long)__float_as_uint(h)
                                      | ((unsigned long long)(unsigned)(s + 1) << 32);
                __hip_atomic_store(&hb1[(s & 1) * 512 + w * 4 + tid], pk,
                                   __ATOMIC_RELAXED, __HIP_MEMORY_SCOPE_AGENT);
                out[(long)tB * 1024 + 512 + w * 4 + tid] = h;
            }
        }
    }
}

// ---------------------------------------------------------------------------
__global__ __launch_bounds__(128) void gather_emb(
    const int* __restrict__ en, const float* __restrict__ emb, float* __restrict__ x0)
{
    const int t = blockIdx.x;
    ((float4*)(x0 + (long)t * 512))[threadIdx.x] =
        ((const float4*)(emb + (long)en[t] * 512))[threadIdx.x];
}

__global__ __launch_bounds__(256) void add_h(
    const float* __restrict__ o2, float* __restrict__ h)
{
    const long i = (long)blockIdx.x * 256 + threadIdx.x;   // 1024*512
    const long t = i >> 9, j = i & 511;
    h[i] = o2[t * 1024 + j] + o2[t * 1024 + 512 + j];
}

__global__ __launch_bounds__(256) void zkl_kernel(
    const float* __restrict__ mu, const float* __restrict__ sp,
    const float* __restrict__ eps, float* __restrict__ z, float* __restrict__ klsum)
{
    __shared__ float w4[4];
    const int i = blockIdx.x * 256 + threadIdx.x;
    float m = mu[i], x = sp[i];
    float sg = (x > 20.f) ? x : log1pf(expf(x));   // softplus
    z[i] = m + eps[i] * sg;
    float kl = 0.5f * (sg * sg + m * m - 1.f) - logf(sg);
#pragma unroll
    for (int o = 1; o < 64; o <<= 1) kl += __shfl_xor(kl, o);
    if ((threadIdx.x & 63) == 0) w4[threadIdx.x >> 6] = kl;
    __syncthreads();
    if (threadIdx.x == 0) atomicAdd(klsum, w4[0] + w4[1] + w4[2] + w4[3]);
}

__global__ __launch_bounds__(64) void pos_kernel(
    const float* __restrict__ z, const float* __restrict__ E_en,
    const int* __restrict__ en, float* __restrict__ pos)
{
    const int t = blockIdx.x, lane = threadIdx.x;
    const float4* zr = (const float4*)(z + (long)t * 512);
    const float4* er = (const float4*)(E_en + (long)en[t] * 512);
    float s = 0.f;
#pragma unroll
    for (int q = 0; q < 2; ++q) {
        float4 a = zr[lane + q * 64], b = er[lane + q * 64];
        s += a.x * b.x + a.y * b.y + a.z * b.z + a.w * b.w;
    }
#pragma unroll
    for (int o = 1; o < 64; o <<= 1) s += __shfl_xor(s, o);
    if (lane == 0) pos[t] = expf(s);
}

__global__ __launch_bounds__(256) void finalize_kernel(
    const float* __restrict__ pos, const float* __restrict__ neg,
    const float* __restrict__ scal, float* __restrict__ out)
{
    __shared__ float w4[4];
    const int tid = threadIdx.x;
    float s = 0.f;
#pragma unroll
    for (int q = 0; q < 4; ++q) {
        int t = tid + q * 256;
        s += pos[t] / (pos[t] + neg[t]);
    }
#pragma unroll
    for (int o = 1; o < 64; o <<= 1) s += __shfl_xor(s, o);
    if ((tid & 63) == 0) w4[tid >> 6] = s;
    __syncthreads();
    if (tid == 0) {
        float sum_x = w4[0] + w4[1] + w4[2] + w4[3];
        // -(sum_x + sum_y - kl) ; sum_y = psum/1024
        out[0] = scal[0] - sum_x - scal[1] * (1.f / 1024.f);
    }
}

// ---------------------------------------------------------------------------
extern "C" void kernel_launch(void* const* d_in, const int* in_sizes, int n_in,
                              void* d_out, int out_size, void* d_ws, size_t ws_size,
                              hipStream_t stream)
{
    const int*   en     = (const int*)d_in[0];
    const int*   fr     = (const int*)d_in[1];
    const int*   en_neg = (const int*)d_in[2];
    const int*   fr_neg = (const int*)d_in[3];
    const float* emb    = (const float*)d_in[4];
    const float* Wih0   = (const float*)d_in[5];
    const float* Whh0   = (const float*)d_in[6];
    const float* b0     = (const float*)d_in[7];
    const float* Wih1   = (const float*)d_in[8];
    const float* Whh1   = (const float*)d_in[9];
    const float* b1     = (const float*)d_in[10];
    const float* Wih2   = (const float*)d_in[11];
    const float* Whh2   = (const float*)d_in[12];
    const float* b2     = (const float*)d_in[13];
    const float* Wmu1   = (const float*)d_in[14];
    const float* bmu1   = (const float*)d_in[15];
    const float* Wmu2   = (const float*)d_in[16];
    const float* bmu2   = (const float*)d_in[17];
    const float* Ws1    = (const float*)d_in[18];
    const float* bs1    = (const float*)d_in[19];
    const float* Ws2    = (const float*)d_in[20];
    const float* bs2    = (const float*)d_in[21];
    const float* E_en   = (const float*)d_in[22];
    const float* E_fr   = (const float*)d_in[23];
    const float* eps    = (const float*)d_in[24];
    float* out = (float*)d_out;

    float* w = (float*)d_ws;
    float* x0   = w;  w += 1024 * 512;
    float* bufA = w;  w += 1024 * 1024;
    float* bufB = w;  w += 1024 * 1024;
    float* Xf   = w;  w += 1024 * 2048;
    float* Xb   = w;  w += 1024 * 2048;
    float* h    = w;  w += 1024 * 512;
    float* tmp  = w;  w += 1024 * 512;
    float* mu   = w;  w += 1024 * 512;
    float* sp   = w;  w += 1024 * 512;
    float* z    = w;  w += 1024 * 512;
    float* pos  = w;  w += 1024;
    float* neg  = w;  w += 1024;
    float* negf = w;  w += 1024;                 // neg..negf contiguous
    unsigned long long* hbuf = (unsigned long long*)w; w += 4096;  // 2x2x512 slots x 8B
    float* scal = w;  w += 2;                    // [klsum, psum]

    // zero accumulators (ws is poisoned 0xAA before every launch)
    hipMemsetAsync(neg, 0, 2048 * sizeof(float), stream);
    hipMemsetAsync(scal, 0, 2 * sizeof(float), stream);

    gather_emb<<<1024, 128, 0, stream>>>(en, emb, x0);

    // ---- layer 0 (in = x0, K=512) -> bufA
    gemm_nt<false, false, 0><<<dim3(16, 32), 256, 0, stream>>>(
        x0, Wih0,               b0,        nullptr, Xf, nullptr, nullptr, 1024, 2048, 512);
    gemm_nt<false, false, 0><<<dim3(16, 32), 256, 0, stream>>>(
        x0, Wih0 + 2048 * 512,  b0 + 2048, nullptr, Xb, nullptr, nullptr, 1024, 2048, 512);
    hipMemsetAsync(hbuf, 0, 4096 * 8, stream);
    lstm_scan<<<128, 256, 0, stream>>>(Xf, Xb, Whh0, bufA, hbuf);

    // ---- layer 1 (in = bufA, K=1024) -> bufB
    gemm_nt<false, false, 0><<<dim3(16, 32), 256, 0, stream>>>(
        bufA, Wih1,               b1,        nullptr, Xf, nullptr, nullptr, 1024, 2048, 1024);
    gemm_nt<false, false, 0><<<dim3(16, 32), 256, 0, stream>>>(
        bufA, Wih1 + 2048 * 1024, b1 + 2048, nullptr, Xb, nullptr, nullptr, 1024, 2048, 1024);
    hipMemsetAsync(hbuf, 0, 4096 * 8, stream);
    lstm_scan<<<128, 256, 0, stream>>>(Xf, Xb, Whh1, bufB, hbuf);

    // ---- layer 2 (in = bufB, K=1024) -> bufA
    gemm_nt<false, false, 0><<<dim3(16, 32), 256, 0, stream>>>(
        bufB, Wih2,               b2,        nullptr, Xf, nullptr, nullptr, 1024, 2048, 1024);
    gemm_nt<false, false, 0><<<dim3(16, 32), 256, 0, stream>>>(
        bufB, Wih2 + 2048 * 1024, b2 + 2048, nullptr, Xb, nullptr, nullptr, 1024, 2048, 1024);
    hipMemsetAsync(hbuf, 0, 4096 * 8, stream);
    lstm_scan<<<128, 256, 0, stream>>>(Xf, Xb, Whh2, bufA, hbuf);

    // h = hf + hb
    add_h<<<2048, 256, 0, stream>>>(bufA, h);

    // inference nets
    gemm_nt<false, true, 0><<<dim3(16, 8), 256, 0, stream>>>(
        h,   Wmu1, bmu1, nullptr, tmp, nullptr, nullptr, 1024, 512, 512);
    gemm_nt<false, false, 0><<<dim3(16, 8), 256, 0, stream>>>(
        tmp, Wmu2, bmu2, nullptr, mu,  nullptr, nullptr, 1024, 512, 512);
    gemm_nt<false, true, 0><<<dim3(16, 8), 256, 0, stream>>>(
        h,   Ws1,  bs1,  nullptr, tmp, nullptr, nullptr, 1024, 512, 512);
    gemm_nt<false, false, 0><<<dim3(16, 8), 256, 0, stream>>>(
        tmp, Ws2,  bs2,  nullptr, sp,  nullptr, nullptr, 1024, 512, 512);

    // z, KL
    zkl_kernel<<<2048, 256, 0, stream>>>(mu, sp, eps, z, scal);

    // scores
    pos_kernel<<<1024, 64, 0, stream>>>(z, E_en, en, pos);
    gemm_nt<true, false, 1><<<dim3(16, 128), 256, 0, stream>>>(
        z, E_en, nullptr, en_neg, neg,  nullptr, nullptr, 1024, 8192, 512);
    gemm_nt<true, false, 1><<<dim3(16, 128), 256, 0, stream>>>(
        z, E_fr, nullptr, fr_neg, negf, nullptr, nullptr, 1024, 8192, 512);
    gemm_nt<true, false, 2><<<dim3(16, 16), 256, 0, stream>>>(
        z, E_fr, nullptr, fr,     nullptr, negf, scal + 1, 1024, 1024, 512);

    finalize_kernel<<<1, 256, 0, stream>>>(pos, neg, scal, out);
}